// Round 3
// baseline (426.854 us; speedup 1.0000x reference)
//
#include <hip/hip_runtime.h>

typedef unsigned short ushort_t;
typedef __bf16 bf16x8 __attribute__((ext_vector_type(8)));
typedef float f32x4 __attribute__((ext_vector_type(4)));

// sizes (fixed by the problem)
#define NB 8
#define BB 2
#define TT 2048
#define DD 2048
#define FF 8192
#define MM (BB * TT)          // 4096 rows
#define BTD ((size_t)BB * TT * DD)   // 8388608

__device__ __forceinline__ unsigned short f2bf(float f) {
  unsigned int u = __float_as_uint(f);
  u += 0x7FFFu + ((u >> 16) & 1u);
  return (unsigned short)(u >> 16);
}

__device__ __forceinline__ float gelu_tanh(float x) {
  float u = 0.7978845608028654f * (x + 0.044715f * x * x * x);
  float e = __expf(2.0f * u);
  float th = 1.0f - 2.0f / (e + 1.0f);   // robust tanh(u), e=inf -> 1
  return 0.5f * x * (1.0f + th);
}

template <int N>
__device__ __forceinline__ void wait_vmcnt() {
  if constexpr (N == 0) asm volatile("s_waitcnt vmcnt(0)" ::: "memory");
  else if constexpr (N == 2) asm volatile("s_waitcnt vmcnt(2)" ::: "memory");
  else if constexpr (N == 4) asm volatile("s_waitcnt vmcnt(4)" ::: "memory");
  else if constexpr (N == 6) asm volatile("s_waitcnt vmcnt(6)" ::: "memory");
}

#define ASYNC_COPY16(gp, lp)                                                   \
  __builtin_amdgcn_global_load_lds(                                            \
      (__attribute__((address_space(1))) void*)(gp),                           \
      (__attribute__((address_space(3))) void*)(lp), 16, 0, 0)

// ---------------------------------------------------------------------------
// fp32 (R x C) -> bf16 transposed (C x R)
__global__ __launch_bounds__(256) void transpose_conv(
    const float* __restrict__ in, ushort_t* __restrict__ out, int R, int C) {
  __shared__ float tile[32][33];
  const int tx = threadIdx.x & 31, ty = threadIdx.x >> 5;
  const int r0 = blockIdx.y * 32, c0 = blockIdx.x * 32;
#pragma unroll
  for (int i = 0; i < 32; i += 8)
    tile[ty + i][tx] = in[(size_t)(r0 + ty + i) * C + (c0 + tx)];
  __syncthreads();
#pragma unroll
  for (int i = 0; i < 32; i += 8)
    out[(size_t)(c0 + ty + i) * R + (r0 + tx)] = f2bf(tile[tx][ty + i]);
}

// ---------------------------------------------------------------------------
// Fused block-attention: one block per (b,t) row.
__global__ __launch_bounds__(256) void attn_fuse(
    const float* __restrict__ blocks, const float* __restrict__ partial,
    const float* __restrict__ proj_w, const float* __restrict__ norm_scale,
    float* __restrict__ h_out, ushort_t* __restrict__ h_bf) {
  const int t = threadIdx.x;
  const int bt = blockIdx.x;
  const size_t rowoff = (size_t)bt * DD;
  const int d0 = t * 4;

  float w[8];
  {
    float4 ns = *(const float4*)(norm_scale + d0);
    float4 pw = *(const float4*)(proj_w + d0);
    w[0] = ns.x * pw.x; w[1] = ns.y * pw.y; w[2] = ns.z * pw.z; w[3] = ns.w * pw.w;
    ns = *(const float4*)(norm_scale + 1024 + d0);
    pw = *(const float4*)(proj_w + 1024 + d0);
    w[4] = ns.x * pw.x; w[5] = ns.y * pw.y; w[6] = ns.z * pw.z; w[7] = ns.w * pw.w;
  }

  float ss[9], dt[9];
#pragma unroll
  for (int n = 0; n < 9; ++n) {
    const float* rp = (n < 8) ? (blocks + (size_t)n * BTD + rowoff)
                              : (partial + rowoff);
    float4 v0 = *(const float4*)(rp + d0);
    float4 v1 = *(const float4*)(rp + 1024 + d0);
    ss[n] = v0.x * v0.x + v0.y * v0.y + v0.z * v0.z + v0.w * v0.w +
            v1.x * v1.x + v1.y * v1.y + v1.z * v1.z + v1.w * v1.w;
    dt[n] = v0.x * w[0] + v0.y * w[1] + v0.z * w[2] + v0.w * w[3] +
            v1.x * w[4] + v1.y * w[5] + v1.z * w[6] + v1.w * w[7];
  }

  __shared__ float red[2][9][4];
  const int lane = t & 63, wv = t >> 6;
#pragma unroll
  for (int n = 0; n < 9; ++n) {
    float a = ss[n], c = dt[n];
#pragma unroll
    for (int off = 32; off > 0; off >>= 1) {
      a += __shfl_down(a, off, 64);
      c += __shfl_down(c, off, 64);
    }
    if (lane == 0) { red[0][n][wv] = a; red[1][n][wv] = c; }
  }
  __syncthreads();
  __shared__ float logit_s[9];
  if (t < 9) {
    float a = red[0][t][0] + red[0][t][1] + red[0][t][2] + red[0][t][3];
    float c = red[1][t][0] + red[1][t][1] + red[1][t][2] + red[1][t][3];
    logit_s[t] = c * rsqrtf(a * (1.0f / (float)DD) + 1e-8f);
  }
  __syncthreads();

  float lg[9], mx = -1e30f;
#pragma unroll
  for (int n = 0; n < 9; ++n) { lg[n] = logit_s[n]; mx = fmaxf(mx, lg[n]); }
  float den = 0.0f;
#pragma unroll
  for (int n = 0; n < 9; ++n) { lg[n] = __expf(lg[n] - mx); den += lg[n]; }
  const float inv = 1.0f / den;

  float h[8] = {0, 0, 0, 0, 0, 0, 0, 0};
#pragma unroll
  for (int n = 0; n < 9; ++n) {
    const float* rp = (n < 8) ? (blocks + (size_t)n * BTD + rowoff)
                              : (partial + rowoff);
    float4 v0 = *(const float4*)(rp + d0);
    float4 v1 = *(const float4*)(rp + 1024 + d0);
    const float a = lg[n] * inv;
    h[0] += a * v0.x; h[1] += a * v0.y; h[2] += a * v0.z; h[3] += a * v0.w;
    h[4] += a * v1.x; h[5] += a * v1.y; h[6] += a * v1.z; h[7] += a * v1.w;
  }

  float4 o0 = {h[0], h[1], h[2], h[3]}, o1 = {h[4], h[5], h[6], h[7]};
  *(float4*)(h_out + rowoff + d0) = o0;
  *(float4*)(h_out + rowoff + 1024 + d0) = o1;
  uint2 p0, p1;
  p0.x = (unsigned)f2bf(h[0]) | ((unsigned)f2bf(h[1]) << 16);
  p0.y = (unsigned)f2bf(h[2]) | ((unsigned)f2bf(h[3]) << 16);
  p1.x = (unsigned)f2bf(h[4]) | ((unsigned)f2bf(h[5]) << 16);
  p1.y = (unsigned)f2bf(h[6]) | ((unsigned)f2bf(h[7]) << 16);
  *(uint2*)(h_bf + rowoff + d0) = p0;
  *(uint2*)(h_bf + rowoff + 1024 + d0) = p1;
}

// ---------------------------------------------------------------------------
// 256-row 4-phase bf16 GEMM with counted vmcnt (m201/T3+T4 schedule).
// BM=256, BK=64, 8 waves (2M x 4N), per-wave output 128 x (BN/4).
// LDS row byte-stride 128, col XOR-swizzle byte ^= ((row&7)<<4), staged via
// pre-swizzled global source (rule #21).  64-row x 64-col chunks; one
// global_load_lds (16B) per thread per chunk.
// Phase MFMA quadrants: P1 (mh0,nh0), P2 (mh0,nh1), P3 (mh1,nh1), P4 (mh1,nh0
// via B re-read).  Stages for tile t+1: P1: A{0,2}+B{0,1}, P2: B{2,3} (BN=256),
// P3: A{1,3}.  Counted waits: end-P2 vmcnt(WP2) covers P3's A-reads; end-P4
// vmcnt(2) covers next tile's P1 reads, leaving A{1,3} in flight. No vmcnt(0)
// in the main loop.
// EPI=0: C = gelu(A@B) -> bf16.  EPI=1: C = A@B + addend -> fp32.
template <int BN, int EPI>
__global__ __launch_bounds__(512) void gemm256(
    const ushort_t* __restrict__ A, const ushort_t* __restrict__ BT,
    const int K, const int N, const int GX, ushort_t* __restrict__ Cb,
    const float* __restrict__ addend, float* __restrict__ Cf) {
  constexpr int BM = 256;
  constexpr int WCN = BN / 4;       // wave col span
  constexpr int MF = 8;             // m-frags per wave
  constexpr int NF = WCN / 16;      // n-frags per wave
  constexpr int NH = NF / 2;        // n-frags per quadrant
  constexpr int NCB = BN / 64;      // B chunks
  constexpr int AUS = BM * 64;      // A region size in ushorts (16384)
  constexpr int WP2 = (BN == 256) ? 6 : 4;

  __shared__ __align__(16) ushort_t lds0[(BM + BN) * 64];
  __shared__ __align__(16) ushort_t lds1[(BM + BN) * 64];

  const int t = threadIdx.x;
  const int lane = t & 63, wv = t >> 6;
  const int wr = wv >> 2, wc = wv & 3;
  const int fr = lane & 15;

  // T1: XCD-aware swizzle (grid % 8 == 0 in both instantiations)
  const int nwg = gridDim.x;
  const int wg = blockIdx.x;
  const int swz = (wg & 7) * (nwg >> 3) + (wg >> 3);
  const int bx = swz % GX, by = swz / GX;
  const int row0 = by * BM, col0 = bx * BN;

  // staging: thread t covers 16B at (row = chunk*64 + t/8, colbyte pre-swz)
  const int sr = t >> 3;
  const int scolb = ((t & 7) * 16) ^ ((sr & 7) << 4);  // inverse-swizzled src
  const ushort_t* gA = A + (size_t)(row0 + sr) * K + (scolb >> 1);
  const ushort_t* gB = BT + (size_t)(col0 + sr) * K + (scolb >> 1);

#define STAGE_A(W, c, KT)                                                      \
  ASYNC_COPY16(gA + (size_t)((c)*64) * K + (KT)*64, &W[(c)*4096 + wv * 512])
#define STAGE_B(W, c, KT)                                                      \
  ASYNC_COPY16(gB + (size_t)((c)*64) * K + (KT)*64,                            \
               &W[AUS + (c)*4096 + wv * 512])

  // frag read offsets: row*128 + ((ks*64 + (lane>>4)*16) ^ ((row&7)<<4));
  // row&7 == fr&7 for every frag row, so the XOR term is lane-constant.
  const int s_lane = (fr & 7) << 4;
  const int offk0 = ((lane >> 4) * 16) ^ s_lane;
  const int offk1 = (64 + (lane >> 4) * 16) ^ s_lane;
  const int aoffA = (wr * 128 + fr) * 128;  // + m*2048
  int boffB[NF];
#pragma unroll
  for (int n = 0; n < NF; ++n)
    boffB[n] = AUS * 2 + (wc * WCN + n * 16 + fr) * 128;

  f32x4 acc[MF][NF];
#pragma unroll
  for (int m = 0; m < MF; ++m)
#pragma unroll
    for (int n = 0; n < NF; ++n) {
      f32x4 z = {0.f, 0.f, 0.f, 0.f};
      acc[m][n] = z;
    }

#define MFMA_(a, b, c) __builtin_amdgcn_mfma_f32_16x16x32_bf16(a, b, c, 0, 0, 0)

#define TILE(Rb, Wb, KT, S)                                                    \
  {                                                                            \
    const char* _L = (const char*)Rb;                                          \
    bf16x8 af[4][2], b0[NH][2], b1[NH][2];                                     \
    /* ---- P1: (mh0, nh0) ---- */                                             \
    _Pragma("unroll") for (int m = 0; m < 4; ++m) {                            \
      af[m][0] = *(const bf16x8*)(_L + aoffA + m * 2048 + offk0);              \
      af[m][1] = *(const bf16x8*)(_L + aoffA + m * 2048 + offk1);              \
    }                                                                          \
    _Pragma("unroll") for (int n = 0; n < NH; ++n) {                           \
      b0[n][0] = *(const bf16x8*)(_L + boffB[n] + offk0);                      \
      b0[n][1] = *(const bf16x8*)(_L + boffB[n] + offk1);                      \
    }                                                                          \
    if (S) {                                                                   \
      STAGE_A(Wb, 0, KT); STAGE_A(Wb, 2, KT);                                  \
      STAGE_B(Wb, 0, KT); STAGE_B(Wb, 1, KT);                                  \
    }                                                                          \
    __builtin_amdgcn_s_barrier();                                              \
    __builtin_amdgcn_s_setprio(1);                                             \
    _Pragma("unroll") for (int m = 0; m < 4; ++m)                              \
      _Pragma("unroll") for (int n = 0; n < NH; ++n) {                         \
        acc[m][n] = MFMA_(af[m][0], b0[n][0], acc[m][n]);                      \
        acc[m][n] = MFMA_(af[m][1], b0[n][1], acc[m][n]);                      \
      }                                                                        \
    __builtin_amdgcn_s_setprio(0);                                             \
    __builtin_amdgcn_s_barrier();                                              \
    /* ---- P2: (mh0, nh1) ---- */                                             \
    _Pragma("unroll") for (int n = 0; n < NH; ++n) {                           \
      b1[n][0] = *(const bf16x8*)(_L + boffB[NH + n] + offk0);                 \
      b1[n][1] = *(const bf16x8*)(_L + boffB[NH + n] + offk1);                 \
    }                                                                          \
    if (S && BN == 256) { STAGE_B(Wb, 2, KT); STAGE_B(Wb, 3, KT); }            \
    __builtin_amdgcn_s_barrier();                                              \
    __builtin_amdgcn_s_setprio(1);                                             \
    _Pragma("unroll") for (int m = 0; m < 4; ++m)                              \
      _Pragma("unroll") for (int n = 0; n < NH; ++n) {                         \
        acc[m][NH + n] = MFMA_(af[m][0], b1[n][0], acc[m][NH + n]);            \
        acc[m][NH + n] = MFMA_(af[m][1], b1[n][1], acc[m][NH + n]);            \
      }                                                                        \
    __builtin_amdgcn_s_setprio(0);                                             \
    if (S) wait_vmcnt<WP2>(); else wait_vmcnt<0>();                            \
    __builtin_amdgcn_s_barrier();                                              \
    /* ---- P3: (mh1, nh1) ---- */                                             \
    _Pragma("unroll") for (int m = 0; m < 4; ++m) {                            \
      af[m][0] = *(const bf16x8*)(_L + aoffA + (4 + m) * 2048 + offk0);        \
      af[m][1] = *(const bf16x8*)(_L + aoffA + (4 + m) * 2048 + offk1);        \
    }                                                                          \
    if (S) { STAGE_A(Wb, 1, KT); STAGE_A(Wb, 3, KT); }                         \
    __builtin_amdgcn_s_barrier();                                              \
    __builtin_amdgcn_s_setprio(1);                                             \
    _Pragma("unroll") for (int m = 0; m < 4; ++m)                              \
      _Pragma("unroll") for (int n = 0; n < NH; ++n) {                         \
        acc[4 + m][NH + n] = MFMA_(af[m][0], b1[n][0], acc[4 + m][NH + n]);    \
        acc[4 + m][NH + n] = MFMA_(af[m][1], b1[n][1], acc[4 + m][NH + n]);    \
      }                                                                        \
    __builtin_amdgcn_s_setprio(0);                                             \
    __builtin_amdgcn_s_barrier();                                              \
    /* ---- P4: (mh1, nh0), B nh0 re-read ---- */                              \
    _Pragma("unroll") for (int n = 0; n < NH; ++n) {                           \
      b0[n][0] = *(const bf16x8*)(_L + boffB[n] + offk0);                      \
      b0[n][1] = *(const bf16x8*)(_L + boffB[n] + offk1);                      \
    }                                                                          \
    __builtin_amdgcn_s_barrier();                                              \
    __builtin_amdgcn_s_setprio(1);                                             \
    _Pragma("unroll") for (int m = 0; m < 4; ++m)                              \
      _Pragma("unroll") for (int n = 0; n < NH; ++n) {                         \
        acc[4 + m][n] = MFMA_(af[m][0], b0[n][0], acc[4 + m][n]);              \
        acc[4 + m][n] = MFMA_(af[m][1], b0[n][1], acc[4 + m][n]);              \
      }                                                                        \
    __builtin_amdgcn_s_setprio(0);                                             \
    if (S) wait_vmcnt<2>();                                                    \
    __builtin_amdgcn_s_barrier();                                              \
  }

  // prologue: stage tile 0 in consumption order, wait for all but A{1,3}
  STAGE_A(lds0, 0, 0); STAGE_A(lds0, 2, 0);
  STAGE_B(lds0, 0, 0); STAGE_B(lds0, 1, 0);
  if (BN == 256) { STAGE_B(lds0, 2, 0); STAGE_B(lds0, 3, 0); }
  STAGE_A(lds0, 1, 0); STAGE_A(lds0, 3, 0);
  wait_vmcnt<2>();
  __builtin_amdgcn_s_barrier();

  const int NT = K >> 6;  // K-tiles (NT even: 32 or 128)
  for (int kt = 0; kt < NT; kt += 2) {
    TILE(lds0, lds1, kt + 1, (kt + 1) < NT);
    TILE(lds1, lds0, kt + 2, (kt + 2) < NT);
  }

  const int r4 = (lane >> 4) * 4;
#pragma unroll
  for (int m = 0; m < MF; ++m) {
    const int grow = row0 + wr * 128 + m * 16 + r4;
#pragma unroll
    for (int n = 0; n < NF; ++n) {
      const int gcol = col0 + wc * WCN + n * 16 + fr;
#pragma unroll
      for (int r = 0; r < 4; ++r) {
        const float v = acc[m][n][r];
        const size_t idx = (size_t)(grow + r) * N + gcol;
        if (EPI == 0) {
          Cb[idx] = f2bf(gelu_tanh(v));
        } else {
          Cf[idx] = v + addend[idx];
        }
      }
    }
  }
#undef TILE
#undef MFMA_
#undef STAGE_A
#undef STAGE_B
}

// ---------------------------------------------------------------------------
extern "C" void kernel_launch(void* const* d_in, const int* in_sizes, int n_in,
                              void* d_out, int out_size, void* d_ws,
                              size_t ws_size, hipStream_t stream) {
  const float* blocks = (const float*)d_in[0];
  const float* partial = (const float*)d_in[1];
  const float* proj_w = (const float*)d_in[2];
  const float* norm_scale = (const float*)d_in[3];
  const float* w1 = (const float*)d_in[4];
  const float* w2 = (const float*)d_in[5];

  float* out = (float*)d_out;
  float* h_out = out;                 // [B,T,D] fp32
  float* new_partial = out + BTD;     // [B,T,D] fp32

  char* ws = (char*)d_ws;
  ushort_t* h_bf = (ushort_t*)ws;                                        // 16 MB
  ushort_t* w1T = (ushort_t*)(ws + (size_t)16777216);                    // 32 MB (F x D)
  ushort_t* w2T = (ushort_t*)(ws + (size_t)16777216 + 33554432);         // 32 MB (D x F)
  ushort_t* act = (ushort_t*)(ws + (size_t)16777216 + 2 * 33554432ull);  // 64 MB (M x F)

  // weight convert + transpose to (N x K) bf16
  transpose_conv<<<dim3(FF / 32, DD / 32), 256, 0, stream>>>(w1, w1T, DD, FF);
  transpose_conv<<<dim3(DD / 32, FF / 32), 256, 0, stream>>>(w2, w2T, FF, DD);

  // fused attention -> h (fp32 out) + h (bf16 for GEMM)
  attn_fuse<<<MM, 256, 0, stream>>>(blocks, partial, proj_w, norm_scale, h_out,
                                    h_bf);

  // FFN: act = gelu(h @ W1) ; new_partial = act @ W2 + partial
  gemm256<256, 0><<<(FF / 256) * (MM / 256), 512, 0, stream>>>(
      h_bf, w1T, DD, FF, FF / 256, act, nullptr, nullptr);
  gemm256<128, 1><<<(DD / 128) * (MM / 256), 512, 0, stream>>>(
      act, w2T, FF, DD, DD / 128, nullptr, partial, new_partial);
}